// Round 1
// baseline (280.399 us; speedup 1.0000x reference)
//
#include <hip/hip_runtime.h>

#define B_TOTAL 65536
#define IMG 28
#define KSZ 3
#define OHW 26
#define FLAT 676    // 26*26
#define HID 100
#define NCLS 10
#define KPAD 800    // 784 padded to multiple of 32
#define NPAD 128    // 100 padded

#define BM 64
#define BK 32

// Kernel 1: fold conv into fc1. Builds W1effT [KPAD][NPAD] (transposed,
// zero-padded) in workspace. W1eff[h][q] = sum_{i,j} conv_w[i,j] *
// w1[h, (qr-i)*26 + (qc-j)] over valid (i,j).
__global__ void build_w1eff(const float* __restrict__ conv_w,
                            const float* __restrict__ w1,
                            float* __restrict__ w1t) {
    int idx = blockIdx.x * blockDim.x + threadIdx.x;
    if (idx >= KPAD * NPAD) return;
    int k = idx >> 7;       // 0..799 (input pixel q)
    int n = idx & 127;      // 0..127 (hidden unit h)
    float val = 0.f;
    if (k < IMG * IMG && n < HID) {
        int qr = k / IMG, qc = k % IMG;
        #pragma unroll
        for (int i = 0; i < KSZ; ++i) {
            int r = qr - i;
            if (r < 0 || r >= OHW) continue;
            #pragma unroll
            for (int j = 0; j < KSZ; ++j) {
                int c = qc - j;
                if (c < 0 || c >= OHW) continue;
                val += conv_w[i * KSZ + j] * w1[n * FLAT + r * OHW + c];
            }
        }
    }
    w1t[idx] = val;
}

// Kernel 2: fused GEMM1 (x @ W1effT, +b1, ReLU) -> LDS -> GEMM2 (@ w2T, +b2).
// Block: 64 samples, 256 threads. Thread (tm=tid>>5, tn=tid&31) computes an
// 8x4 register tile: rows tm*8+rr, cols tn*4+cc of the 64x128 h1 tile.
__global__ __launch_bounds__(256) void fused_fwd(
    const float* __restrict__ x,     // [65536][784]
    const float* __restrict__ w1t,   // [800][128]
    const float* __restrict__ b1,    // [100]
    const float* __restrict__ w2,    // [10][100]
    const float* __restrict__ b2,    // [10]
    float* __restrict__ out)         // [65536][10]
{
    __shared__ float Xs[BM][BK + 1];       // +1 pad: conflict-free col reads
    __shared__ float Ws[BK][NPAD];         // reads are 16B-stride, no pad
    __shared__ float H1[BM][NPAD + 4];     // +4 pad keeps 16B align, breaks 128-stride

    const int tid = threadIdx.x;
    const int tn = tid & 31;
    const int tm = tid >> 5;
    const int row0 = blockIdx.x * BM;

    float acc[8][4];
    #pragma unroll
    for (int i = 0; i < 8; ++i)
        #pragma unroll
        for (int j = 0; j < 4; ++j) acc[i][j] = 0.f;

    for (int k0 = 0; k0 < KPAD; k0 += BK) {
        // stage X tile (64 rows x 32 k), coalesced 32-lane row segments
        {
            const int col = tid & 31;
            const int rbase = tid >> 5;
            const int kk = k0 + col;
            #pragma unroll
            for (int i = 0; i < 8; ++i) {
                int r = rbase + 8 * i;
                float v = (kk < IMG * IMG) ? x[(size_t)(row0 + r) * (IMG * IMG) + kk] : 0.f;
                Xs[r][col] = v;
            }
        }
        // stage W tile (32 k x 128 n), fully coalesced
        {
            #pragma unroll
            for (int i = 0; i < 16; ++i) {
                int idx = tid + 256 * i;
                int k = idx >> 7;
                int n = idx & 127;
                Ws[k][n] = w1t[(size_t)(k0 + k) * NPAD + n];
            }
        }
        __syncthreads();

        #pragma unroll 8
        for (int k = 0; k < BK; ++k) {
            float a[8];
            #pragma unroll
            for (int rr = 0; rr < 8; ++rr) a[rr] = Xs[tm * 8 + rr][k];
            float4 b = *(const float4*)&Ws[k][tn * 4];
            #pragma unroll
            for (int rr = 0; rr < 8; ++rr) {
                acc[rr][0] += a[rr] * b.x;
                acc[rr][1] += a[rr] * b.y;
                acc[rr][2] += a[rr] * b.z;
                acc[rr][3] += a[rr] * b.w;
            }
        }
        __syncthreads();
    }

    // bias + ReLU -> H1 in LDS
    #pragma unroll
    for (int cc = 0; cc < 4; ++cc) {
        int n = tn * 4 + cc;
        float bias = (n < HID) ? b1[n] : 0.f;
        #pragma unroll
        for (int rr = 0; rr < 8; ++rr) {
            float v = acc[rr][cc] + bias;
            H1[tm * 8 + rr][n] = v > 0.f ? v : 0.f;
        }
    }
    __syncthreads();

    // layer 2: 64 samples x 10 classes, dot over 100 hidden
    for (int p = tid; p < BM * NCLS; p += 256) {
        int s = p / NCLS;
        int c = p - s * NCLS;
        float sum = b2[c];
        #pragma unroll 4
        for (int h = 0; h < HID; ++h)
            sum += H1[s][h] * w2[c * HID + h];
        out[(size_t)(row0 + s) * NCLS + c] = sum;
    }
}

extern "C" void kernel_launch(void* const* d_in, const int* in_sizes, int n_in,
                              void* d_out, int out_size, void* d_ws, size_t ws_size,
                              hipStream_t stream) {
    const float* x      = (const float*)d_in[0];
    const float* conv_w = (const float*)d_in[1];
    const float* w1     = (const float*)d_in[2];
    const float* b1     = (const float*)d_in[3];
    const float* w2     = (const float*)d_in[4];
    const float* b2     = (const float*)d_in[5];
    float* out = (float*)d_out;
    float* w1t = (float*)d_ws;   // KPAD*NPAD*4 = 409.6 KB

    build_w1eff<<<(KPAD * NPAD + 255) / 256, 256, 0, stream>>>(conv_w, w1, w1t);
    fused_fwd<<<B_TOTAL / BM, 256, 0, stream>>>(x, w1t, b1, w2, b2, out);
}

// Round 2
// 64.960 us; speedup vs baseline: 4.3165x; 4.3165x over previous
//
#include <hip/hip_runtime.h>

#define IMG 28
#define FLATK 784     // 28*28
#define OHW 26
#define FLAT 676      // 26*26
#define HID 100
#define NCLS 10
#define KP 800        // K padded to 25*32
#define BM 128        // rows per block
#define NSTEPS 25     // KP / 32

typedef __attribute__((ext_vector_type(8))) short bfrag;   // 8 bf16 (4 VGPR)
typedef __attribute__((ext_vector_type(4))) float f32x4;

__device__ __forceinline__ unsigned short f2bf(float f) {
    unsigned u = __float_as_uint(f);
    u = (u + 0x7fffu + ((u >> 16) & 1u)) >> 16;   // RNE
    return (unsigned short)u;
}

// Kernel 1: fold conv into fc1 -> bf16 W1eff [128 n][800 k] (zero-padded),
// and w2 -> bf16 [16 n][128 k] (zero-padded).
__global__ void build_weights(const float* __restrict__ conv_w,
                              const float* __restrict__ w1,
                              const float* __restrict__ w2,
                              unsigned short* __restrict__ w1b,
                              unsigned short* __restrict__ w2b) {
    int idx = blockIdx.x * blockDim.x + threadIdx.x;
    if (idx < 128 * KP) {
        int n = idx / KP, k = idx - n * KP;
        float val = 0.f;
        if (n < HID && k < FLATK) {
            int qr = k / IMG, qc = k % IMG;
            #pragma unroll
            for (int i = 0; i < 3; ++i) {
                int r = qr - i;
                if (r < 0 || r >= OHW) continue;
                #pragma unroll
                for (int j = 0; j < 3; ++j) {
                    int c = qc - j;
                    if (c < 0 || c >= OHW) continue;
                    val += conv_w[i * 3 + j] * w1[n * FLAT + r * OHW + c];
                }
            }
        }
        w1b[idx] = f2bf(val);
    } else {
        int t = idx - 128 * KP;
        if (t < 16 * 128) {
            int n = t >> 7, k = t & 127;
            float v = (n < NCLS && k < HID) ? w2[n * HID + k] : 0.f;
            w2b[t] = f2bf(v);
        }
    }
}

// Kernel 2: fused x->conv+fc1(relu)->fc2 via bf16 MFMA.
// 256 threads = 4 waves; block computes 128 rows. Wave wv owns rows
// [wv*32, wv*32+32). A staged via global_load_lds with XOR-swizzled SOURCE
// addresses (LDS dest linear); reads apply the same swizzle.
__global__ __launch_bounds__(256) void fused_fwd(
    const float* __restrict__ x,              // [65536][784] f32
    const unsigned short* __restrict__ w1b,   // [128][800] bf16
    const float* __restrict__ b1,             // [100]
    const unsigned short* __restrict__ w2b,   // [16][128] bf16
    const float* __restrict__ b2,             // [10]
    float* __restrict__ out)                  // [65536][10] f32
{
    // A double buffer: 2 x [128 rows][32 f32] = 2 x 16 KB.
    // h1 (after main loop, aliased): [128][136] bf16 = 34816 B.
    __shared__ char smem[34816] __attribute__((aligned(128)));

    const int tid  = threadIdx.x;
    const int lane = tid & 63;
    const int wv   = tid >> 6;
    const int row0 = blockIdx.x * BM;

    // staging source geometry: dest phys = chunk*1024 + lane*16 (linear);
    // logical = phys ^ ((row&7)<<4)  =>  per-lane source col swizzle
    const int lrow = lane >> 3;                     // row within 8-row chunk
    const int cfl  = ((lane & 7) ^ lrow) * 4;       // source col (floats)

    f32x4 acc[2][8];
    #pragma unroll
    for (int m = 0; m < 2; ++m)
        #pragma unroll
        for (int n = 0; n < 8; ++n)
            acc[m][n] = f32x4{0.f, 0.f, 0.f, 0.f};

    auto stage = [&](int k0, unsigned bufoff) {
        #pragma unroll
        for (int c = 0; c < 4; ++c) {
            int chunk = (wv << 2) + c;
            int row = (chunk << 3) + lrow;
            int col = k0 + cfl;
            if (col >= FLATK) col -= FLATK;   // pad lanes: read safe garbage (B rows are 0 there)
            const float* g = x + (size_t)(row0 + row) * FLATK + col;
            __builtin_amdgcn_global_load_lds(
                (const __attribute__((address_space(1))) void*)g,
                (__attribute__((address_space(3))) void*)(smem + bufoff + chunk * 1024),
                16, 0, 0);
        }
    };

    auto compute = [&](int k0, unsigned bufoff) {
        // A fragments: lane holds row (lane&15), k = (lane>>4)*8 .. +8
        bfrag af[2];
        #pragma unroll
        for (int mf = 0; mf < 2; ++mf) {
            int r = (wv << 5) + (mf << 4) + (lane & 15);
            unsigned alog = ((unsigned)r << 7) + (unsigned)((lane >> 4) << 5);
            unsigned sw = (unsigned)((r & 7) << 4);
            f32x4 lo = *(const f32x4*)(smem + bufoff + (alog ^ sw));
            f32x4 hi = *(const f32x4*)(smem + bufoff + ((alog + 16u) ^ sw));
            af[mf][0] = (short)f2bf(lo.x); af[mf][1] = (short)f2bf(lo.y);
            af[mf][2] = (short)f2bf(lo.z); af[mf][3] = (short)f2bf(lo.w);
            af[mf][4] = (short)f2bf(hi.x); af[mf][5] = (short)f2bf(hi.y);
            af[mf][6] = (short)f2bf(hi.z); af[mf][7] = (short)f2bf(hi.w);
        }
        // B fragments straight from L2-resident w1b: lane holds col (lane&15)
        #pragma unroll
        for (int nt = 0; nt < 8; ++nt) {
            const bfrag bw = *(const bfrag*)(w1b + ((size_t)((nt << 4) + (lane & 15))) * KP
                                             + k0 + ((lane >> 4) << 3));
            acc[0][nt] = __builtin_amdgcn_mfma_f32_16x16x32_bf16(af[0], bw, acc[0][nt], 0, 0, 0);
            acc[1][nt] = __builtin_amdgcn_mfma_f32_16x16x32_bf16(af[1], bw, acc[1][nt], 0, 0, 0);
        }
    };

    stage(0, 0u);
    #pragma unroll 2
    for (int s = 0; s < NSTEPS; ++s) {
        unsigned cur = (s & 1) ? 16384u : 0u;
        asm volatile("s_waitcnt vmcnt(0)" ::: "memory");  // own staging DMA done
        __syncthreads();                                   // everyone's staging done
        if (s + 1 < NSTEPS) stage((s + 1) << 5, cur ^ 16384u);
        compute(s << 5, cur);
    }
    __syncthreads();   // all A reads done before aliasing smem with h1

    // epilogue 1: bias + relu -> bf16 h1 in LDS [128][136]
    unsigned short (*H1)[136] = (unsigned short (*)[136])smem;
    #pragma unroll
    for (int nt = 0; nt < 8; ++nt) {
        int col = (nt << 4) + (lane & 15);
        float bias = (col < HID) ? b1[col] : 0.f;
        #pragma unroll
        for (int mf = 0; mf < 2; ++mf) {
            int rbase = (wv << 5) + (mf << 4) + ((lane >> 4) << 2);
            #pragma unroll
            for (int q = 0; q < 4; ++q) {
                float v = acc[mf][nt][q] + bias;
                H1[rbase + q][col] = f2bf(fmaxf(v, 0.f));
            }
        }
    }
    __syncthreads();

    // layer 2: [128 rows] x [16 cols] over K=128 (pad cols/k are exact zeros)
    f32x4 acc2[2] = {f32x4{0.f,0.f,0.f,0.f}, f32x4{0.f,0.f,0.f,0.f}};
    #pragma unroll
    for (int ks = 0; ks < 4; ++ks) {
        const bfrag bw = *(const bfrag*)(w2b + (lane & 15) * 128 + (ks << 5) + ((lane >> 4) << 3));
        #pragma unroll
        for (int mf = 0; mf < 2; ++mf) {
            int r = (wv << 5) + (mf << 4) + (lane & 15);
            const bfrag ah = *(const bfrag*)&H1[r][(ks << 5) + ((lane >> 4) << 3)];
            acc2[mf] = __builtin_amdgcn_mfma_f32_16x16x32_bf16(ah, bw, acc2[mf], 0, 0, 0);
        }
    }

    int col = lane & 15;
    if (col < NCLS) {
        float bias2 = b2[col];
        #pragma unroll
        for (int mf = 0; mf < 2; ++mf) {
            int rbase = row0 + (wv << 5) + (mf << 4) + ((lane >> 4) << 2);
            #pragma unroll
            for (int q = 0; q < 4; ++q)
                out[(size_t)(rbase + q) * NCLS + col] = acc2[mf][q] + bias2;
        }
    }
}

extern "C" void kernel_launch(void* const* d_in, const int* in_sizes, int n_in,
                              void* d_out, int out_size, void* d_ws, size_t ws_size,
                              hipStream_t stream) {
    const float* x      = (const float*)d_in[0];
    const float* conv_w = (const float*)d_in[1];
    const float* w1     = (const float*)d_in[2];
    const float* b1     = (const float*)d_in[3];
    const float* w2     = (const float*)d_in[4];
    const float* b2     = (const float*)d_in[5];
    float* out = (float*)d_out;

    unsigned short* w1b = (unsigned short*)d_ws;               // 128*800*2 = 204.8 KB
    unsigned short* w2b = w1b + 128 * KP;                      // 16*128*2  = 4 KB

    build_weights<<<(128 * KP + 16 * 128) / 256, 256, 0, stream>>>(conv_w, w1, w2, w1b, w2b);
    fused_fwd<<<65536 / BM, 256, 0, stream>>>(x, w1b, b1, w2b, b2, out);
}